// Round 1
// baseline (170.478 us; speedup 1.0000x reference)
//
#include <hip/hip_runtime.h>

// x: (4, 32, 256, 256) fp32. WINDOW=16, STRIDE=8, EPS=1e-6.
// out[b, l, c, ph, pw] = x[b, c, ho*8+ph, wo*8+pw] + EPS * sum(16x16 patch),
// l = ho*31 + wo, out shape (4, 961, 32, 16, 16)  (~126 MB writes, 33.5 MB input).
//
// Strategy (flat gather, v2): one WAVE per output patch (b, c, l).
//  - lane lo: row r = lo>>2, col-quad q = lo&3 -> float4 of x, 64B-coalesced
//    per patch row. No LDS, no barriers -> no phase-lockstep across resident
//    blocks; loads and stores stay in flight continuously.
//  - patch sum = per-lane 4-sum + 6-step shfl_xor butterfly (in-register).
//  - store: lane lo covers out floats lo*4..lo*4+3 -> each wave stores a
//    contiguous 1 KB; the block's 4 waves take consecutive c -> 4 KB
//    contiguous per block. Nontemporal (streaming) store: output is never
//    re-read, keep L2 for x.
//  - bijective XCD swizzle on the flat block id: each XCD's resident blocks
//    cluster in l (and a fixed 4-channel group) -> per-XCD x working set
//    ~4 MB ~= one XCD's L2, so the ~3.75x patch-overlap re-reads hit L2/L3.

#define BB   4
#define CC   32
#define HH   256
#define WW   256
#define STR  8
#define HOC  31
#define WOC  31
#define LL   (HOC * WOC)   // 961
#define EPSF 1e-6f
#define NXCD 8
#define CGRP 4             // channels per block (1 per wave)
#define NGY  (CC / CGRP)   // 8 c-groups

typedef float f4 __attribute__((ext_vector_type(4)));

__global__ __launch_bounds__(256) void
extract_patches_flat(const float* __restrict__ x, float* __restrict__ out) {
    // ---- flat hw block id -> XCD-chunked swizzle (nwg % 8 == 0) ----
    const int nwg  = LL * NGY * BB;                 // 30752
    const int cpx  = nwg / NXCD;                    // 3844
    const int hwid = blockIdx.x + LL * (blockIdx.y + NGY * blockIdx.z);
    const int swz  = (hwid % NXCD) * cpx + (hwid / NXCD);

    // decode: l fastest -> contiguous swz = contiguous l within one (gy, b)
    const int l    = swz % LL;
    const int rest = swz / LL;                      // 0..31
    const int gy   = rest & (NGY - 1);              // c-group 0..7
    const int b    = rest >> 3;                     // 0..3

    const int wave = threadIdx.x >> 6;
    const int lane = threadIdx.x & 63;
    const int c    = gy * CGRP + wave;

    const int ho = l / WOC;
    const int wo = l - ho * WOC;
    const int r  = lane >> 2;                       // patch row 0..15
    const int q  = lane & 3;                        // col quad 0..3

    // ---- gather: one float4 of x per lane (16B aligned: wo*8 + q*4) ----
    const float* px = x
        + (((size_t)(b * CC + c) * HH + (size_t)(ho * STR + r)) * WW
           + (size_t)(wo * STR + q * 4));
    const f4 v = *(const f4*)px;

    // ---- patch sum: 4-sum + butterfly over all 64 lanes ----
    float s = v.x + v.y + v.z + v.w;
#pragma unroll
    for (int d = 1; d < 64; d <<= 1)
        s += __shfl_xor(s, d, 64);

    const f4 o = v + (EPSF * s);                    // splat add

    // ---- store: contiguous 1 KB per wave, 4 KB per block ----
    float* po = out + (((size_t)b * LL + l) * CC + c) * 256 + (size_t)(lane * 4);
    __builtin_nontemporal_store(o, (f4*)po);
}

extern "C" void kernel_launch(void* const* d_in, const int* in_sizes, int n_in,
                              void* d_out, int out_size, void* d_ws, size_t ws_size,
                              hipStream_t stream) {
    const float* x = (const float*)d_in[0];
    float* out = (float*)d_out;

    dim3 grid(LL, NGY, BB);   // (961, 8, 4) = 30752 blocks, 1 wave/patch
    dim3 block(256);
    extract_patches_flat<<<grid, block, 0, stream>>>(x, out);
}